// Round 18
// baseline (1517.248 us; speedup 1.0000x reference)
//
#include <hip/hip_runtime.h>

// GCNEncoder — round 18.
// r17 clean: 1081us (fused1 219 parked; prep_k merge kept).
// r18: kNN chain rework — per-block top-10 fused into dist_k epilogue (16-lane
// shfl butterfly, lex (value,idx) compare identical to topk_k), candidates
// [row][16 jblk][10] merged by tiny topm_k. Deletes the 16.8MB/batch dist
// matrix round-trip (~540MB total). Index sets provably identical (union-of-
// block-top10 contains global top10; stable lex tie-break preserved).

typedef float f4 __attribute__((ext_vector_type(4)));
typedef float f32x4 __attribute__((ext_vector_type(4)));
typedef short bf16x8 __attribute__((ext_vector_type(8)));

#define BNRSQ 0.9999950000374997f  // 1/sqrt(1+1e-5)

__device__ __forceinline__ float gelu_f(float x){
  float a = 0.7978845608028654f * (x + 0.044715f * x * x * x);
  float e = __expf(2.0f * a);
  float t = 1.0f - 2.0f / (e + 1.0f);   // tanh(a), safe at +/-inf
  return 0.5f * x * (1.0f + t);
}

__device__ __forceinline__ short f2b(float x){            // fp32 -> bf16 RNE
  unsigned u = __float_as_uint(x);
  unsigned r = (u + 0x7fffu + ((u >> 16) & 1u)) >> 16;
  return (short)r;
}
__device__ __forceinline__ float b2f(short s){
  return __uint_as_float(((unsigned)(unsigned short)s) << 16);
}

// ---------------- merged weight prep (segmented by blockIdx.x; 2750 blocks total)
__global__ void prep_k(const float* __restrict__ w11, const float* __restrict__ w12,
                       const float* __restrict__ w21, const float* __restrict__ w22,
                       const float* __restrict__ w31, const float* __restrict__ w32,
                       float* __restrict__ WaT11, float* __restrict__ WdT11,
                       float* __restrict__ Wr12, short* __restrict__ W21sb,
                       short* __restrict__ W22b, short* __restrict__ W31b,
                       short* __restrict__ W32b){
  const int bid = blockIdx.x;
  const int t = threadIdx.x;
  if (bid < 76){
    int split = bid >= 38;
    int id = (split ? bid - 38 : bid) * 256 + t;
    if (id < 64 * 152){
      int c = id / 152, o = id - c * 152;
      float w0 = w11[(size_t)o * 128 + c];
      float v = split ? (w11[(size_t)o * 128 + 64 + c] - w0) : w0;
      (split ? WdT11 : WaT11)[id] = v;
    }
  } else if (bid < 190){
    int id = (bid - 76) * 256 + t;
    if (id < 38 * 192 * 4){
      int i = id & 3, c = (id >> 2) % 192, kq = id / 768;
      int k = kq * 4 + i;
      float v = 0.f;
      if (c < 181 && k < 152) v = w12[(size_t)c * 152 + k];
      Wr12[id] = v;
    }
  } else if (bid < 1086){
    int n = bid - 190;
    if (t < 192){
      short v = 0;
      if (t < 181){
        if (n < 430) v = f2b(w21[(size_t)n * 362 + t]);
        else if (n >= 448 && n < 878){
          int m = n - 448;
          v = f2b(w21[(size_t)m * 362 + 181 + t] - w21[(size_t)m * 362 + t]);
        }
      }
      W21sb[(size_t)n * 192 + t] = v;
    }
  } else if (bid < 1598){
    int n = bid - 1086;
    for (int k = t; k < 448; k += 256){
      short v = 0;
      if (k < 430) v = f2b(w22[(size_t)n * 430 + k]);
      W22b[(size_t)n * 448 + k] = v;
    }
  } else if (bid < 2238){
    int n = bid - 1598;
    for (int k = t; k < 704; k += 256){
      short v = 0;
      if (n < 595 && k < 693) v = f2b(w31[(size_t)n * 693 + k]);
      W31b[(size_t)n * 704 + k] = v;
    }
  } else {
    int n = bid - 2238;
    for (int k = t; k < 640; k += 256){
      short v = 0;
      if (k < 595) v = f2b(w32[(size_t)n * 595 + k]);
      W32b[(size_t)n * 640 + k] = v;
    }
  }
}

// ---------------- transpose (B,64,2048) -> (B,2048,64)
__global__ __launch_bounds__(256) void transpose_k(const float* __restrict__ x, float* __restrict__ xt){
  __shared__ float tile[64][65];
  int b = blockIdx.y;
  int n0 = blockIdx.x * 64;
  int t = threadIdx.x;
  int a = t & 63, r = t >> 6;
  #pragma unroll
  for (int s = 0; s < 16; s++){
    int c = r + s * 4;
    tile[c][a] = x[((size_t)b * 64 + c) * 2048 + n0 + a];
  }
  __syncthreads();
  #pragma unroll
  for (int s = 0; s < 16; s++){
    int n = r + s * 4;
    xt[((size_t)b * 2048 + n0 + n) * 64 + a] = tile[a][n];
  }
}

// ---------------- row squared norms (wave per row), ld-aware
__global__ __launch_bounds__(256) void sqnorm_k(const float* __restrict__ X, float* __restrict__ sq,
                                                int C, int ld, int npts){
  int gid = blockIdx.x * blockDim.x + threadIdx.x;
  int wid = gid >> 6, lane = gid & 63;
  if (wid >= npts) return;
  const float* row = X + (size_t)wid * ld;
  float s = 0.f;
  for (int c = lane; c < C; c += 64){ float v = row[c]; s += v * v; }
  #pragma unroll
  for (int off = 32; off; off >>= 1) s += __shfl_xor(s, off);
  if (lane == 0) sq[wid] = s;
}

// ---------------- dist+blocktop10: 128x128 tile, 8x8 acc, batches via z.
// Epilogue: per row, top-10 of this block's 128 cols via 16-lane lex butterfly;
// candidates -> candV/candI [z][2048][16 jblk][10]. No dist matrix materialized.
__global__ __launch_bounds__(256) void dist_k(const float* __restrict__ X, const float* __restrict__ sq,
                                              float* __restrict__ candV, int* __restrict__ candI,
                                              int C, int ldx){
  __shared__ float As[16][132];
  __shared__ float Bs[16][132];
  const int z = blockIdx.z;
  const float* Xb = X + (size_t)z * 2048 * ldx;
  const float* sqb = sq + (z << 11);
  const int i0 = blockIdx.y * 128, j0 = blockIdx.x * 128;
  const int t = threadIdx.x;
  const int ti = t >> 4, tj = t & 15;
  const int r = t & 127, q8 = (t >> 7) * 8;
  float acc[2][2][4][4];
  #pragma unroll
  for (int a = 0; a < 2; a++)
    #pragma unroll
    for (int b = 0; b < 2; b++)
      #pragma unroll
      for (int u = 0; u < 4; u++)
        #pragma unroll
        for (int v = 0; v < 4; v++) acc[a][b][u][v] = 0.f;
  const float* Ag = Xb + (size_t)(i0 + r) * ldx + q8;
  const float* Bg = Xb + (size_t)(j0 + r) * ldx + q8;
  for (int c0 = 0; c0 < C; c0 += 16){
    f4 av0 = *(const f4*)(Ag + c0);
    f4 av1 = *(const f4*)(Ag + c0 + 4);
    f4 bv0 = *(const f4*)(Bg + c0);
    f4 bv1 = *(const f4*)(Bg + c0 + 4);
    __syncthreads();
    #pragma unroll
    for (int i = 0; i < 4; i++){
      As[q8 + i][r] = av0[i];  As[q8 + 4 + i][r] = av1[i];
      Bs[q8 + i][r] = bv0[i];  Bs[q8 + 4 + i][r] = bv1[i];
    }
    __syncthreads();
    #pragma unroll
    for (int k = 0; k < 16; k++){
      f4 a0 = *(const f4*)&As[k][ti * 4];
      f4 a1 = *(const f4*)&As[k][ti * 4 + 64];
      f4 b0 = *(const f4*)&Bs[k][tj * 4];
      f4 b1 = *(const f4*)&Bs[k][tj * 4 + 64];
      #pragma unroll
      for (int u = 0; u < 4; u++)
        #pragma unroll
        for (int v = 0; v < 4; v++){
          acc[0][0][u][v] += a0[u] * b0[v];
          acc[0][1][u][v] += a0[u] * b1[v];
          acc[1][0][u][v] += a1[u] * b0[v];
          acc[1][1][u][v] += a1[u] * b1[v];
        }
    }
  }
  // acc -> distances in place (same arithmetic as before: si + sj - 2*dot)
  #pragma unroll
  for (int ia = 0; ia < 2; ia++)
    #pragma unroll
    for (int u = 0; u < 4; u++){
      int i = i0 + ia * 64 + ti * 4 + u;
      float si = sqb[i];
      #pragma unroll
      for (int jb = 0; jb < 2; jb++)
        #pragma unroll
        for (int v = 0; v < 4; v++){
          int j = j0 + jb * 64 + tj * 4 + v;
          acc[ia][jb][u][v] = si + sqb[j] - 2.0f * acc[ia][jb][u][v];
        }
    }
  // per-row block-local top-10: 16 lanes (same ti) hold the row's 128 cols (8 each)
  const int bj = blockIdx.x;
  #pragma unroll
  for (int ia = 0; ia < 2; ia++)
    #pragma unroll
    for (int u = 0; u < 4; u++){
      int rrow = i0 + ia * 64 + ti * 4 + u;
      unsigned alive = 0xFFu;
      size_t cbase = (((size_t)z * 2048 + rrow) * 16 + bj) * 10;
      for (int it = 0; it < 10; ++it){
        float bv = 3.0e38f; int bi = 0x7fffffff;
        #pragma unroll
        for (int s = 0; s < 8; s++){
          if (alive & (1u << s)){
            int jb = s >> 2, v = s & 3;
            float x = acc[ia][jb][u][v];
            int xi = j0 + jb * 64 + tj * 4 + v;
            if (x < bv || (x == bv && xi < bi)){ bv = x; bi = xi; }
          }
        }
        #pragma unroll
        for (int off = 1; off < 16; off <<= 1){
          float ov = __shfl_xor(bv, off);
          int   oi = __shfl_xor(bi, off);
          if (ov < bv || (ov == bv && oi < bi)){ bv = ov; bi = oi; }
        }
        #pragma unroll
        for (int s = 0; s < 8; s++){
          int jb = s >> 2, v = s & 3;
          if (j0 + jb * 64 + tj * 4 + v == bi) alive &= ~(1u << s);
        }
        if (tj == 0){ candV[cbase + it] = bv; candI[cbase + it] = bi; }
      }
    }
}

// ---------------- merge 16x10 candidates per row -> final top-10 (wave per row)
__global__ __launch_bounds__(256) void topm_k(const float* __restrict__ candV,
                                              const int* __restrict__ candI,
                                              int* __restrict__ idxout){
  int z = blockIdx.y;
  int lane = threadIdx.x & 63;
  int row = blockIdx.x * 4 + (threadIdx.x >> 6);
  size_t base = ((size_t)z * 2048 + row) * 160;
  float v[3]; int vi[3];
  #pragma unroll
  for (int s = 0; s < 3; s++){
    int slot = lane + s * 64;
    if (slot < 160){ v[s] = candV[base + slot]; vi[s] = candI[base + slot]; }
    else { v[s] = 3.0e38f; vi[s] = 0x7fffffff; }
  }
  int* outp = idxout + (size_t)z * 20480 + (size_t)row * 10;
  for (int it = 0; it < 10; ++it){
    float bv = 3.0e38f; int bi = 0x7fffffff;
    #pragma unroll
    for (int s = 0; s < 3; s++){
      if (v[s] < bv || (v[s] == bv && vi[s] < bi)){ bv = v[s]; bi = vi[s]; }
    }
    #pragma unroll
    for (int off = 32; off; off >>= 1){
      float ov = __shfl_xor(bv, off);
      int   oi = __shfl_xor(bi, off);
      if (ov < bv || (ov == bv && oi < bi)){ bv = ov; bi = oi; }
    }
    #pragma unroll
    for (int s = 0; s < 3; s++) if (vi[s] == bi) v[s] = 3.0e38f;
    if (lane == 0) outp[it] = bi;
  }
}

// ---------------- dual GEMM fp32 (stage-1 only): Y = A*B1, Z = A*B2
__global__ __launch_bounds__(256) void yz_k(const float* __restrict__ Amat, int C,
                                            const float* __restrict__ B1, const float* __restrict__ B2,
                                            int O, float* __restrict__ Y, float* __restrict__ Z){
  __shared__ float As[16][68];
  __shared__ float B1s[16][68];
  __shared__ float B2s[16][68];
  int m0 = blockIdx.y * 64, o0 = blockIdx.x * 64;
  int t = threadIdx.x;
  int cc = t & 15, rr = t >> 4;
  int oo = t & 63, kk = t >> 6;
  float accY[4][4], accZ[4][4];
  #pragma unroll
  for (int u = 0; u < 4; u++)
    #pragma unroll
    for (int v = 0; v < 4; v++){ accY[u][v] = 0.f; accZ[u][v] = 0.f; }
  for (int c0 = 0; c0 < C; c0 += 16){
    #pragma unroll
    for (int u = 0; u < 4; u++){
      int ii = rr + u * 16;
      As[cc][ii] = ((c0 + cc) < C) ? Amat[(size_t)(m0 + ii) * C + c0 + cc] : 0.f;
    }
    #pragma unroll
    for (int u = 0; u < 4; u++){
      int c = kk * 4 + u;
      bool ok = ((c0 + c) < C) && ((o0 + oo) < O);
      B1s[c][oo] = ok ? B1[(size_t)(c0 + c) * O + o0 + oo] : 0.f;
      B2s[c][oo] = ok ? B2[(size_t)(c0 + c) * O + o0 + oo] : 0.f;
    }
    __syncthreads();
    #pragma unroll
    for (int k = 0; k < 16; k++){
      f4 a  = *(const f4*)&As[k][rr * 4];
      f4 b1 = *(const f4*)&B1s[k][cc * 4];
      f4 b2 = *(const f4*)&B2s[k][cc * 4];
      #pragma unroll
      for (int u = 0; u < 4; u++)
        #pragma unroll
        for (int v = 0; v < 4; v++){
          accY[u][v] += a[u] * b1[v];
          accZ[u][v] += a[u] * b2[v];
        }
    }
    __syncthreads();
  }
  #pragma unroll
  for (int u = 0; u < 4; u++){
    int m = m0 + rr * 4 + u;
    #pragma unroll
    for (int v = 0; v < 4; v++){
      int o = o0 + cc * 4 + v;
      if (o < O){
        Y[(size_t)m * O + o] = accY[u][v];
        Z[(size_t)m * O + o] = accZ[u][v];
      }
    }
  }
}

// ---------------- stage-1 fused v5 (fp32, r14-exact): 4 pts/block, kh half-wave k-split,
// cg 32 colgroups, acc[5][6]. LDS 24.5KB -> 6 blocks/CU. Epilogue: x1t + x1b + sq2.
__global__ __launch_bounds__(256) void fused1_k(
    const float* __restrict__ Y1, const float* __restrict__ Z1,
    const int* __restrict__ idx, const float* __restrict__ Wr12,
    const float* __restrict__ bb11, const float* __restrict__ gg11, const float* __restrict__ tt11,
    const float* __restrict__ bb12, const float* __restrict__ gg12, const float* __restrict__ tt12,
    float* __restrict__ x1t, short* __restrict__ x1b, float* __restrict__ sq2){
  __shared__ float h1[40][152];
  __shared__ int sidx[40];
  const int n0 = blockIdx.x * 4;
  const int t = threadIdx.x;
  if (t < 40) sidx[t] = idx[(size_t)n0 * 10 + t];
  __syncthreads();
  const int base = (n0 >> 11) << 11;
  {
    const int tc = t & 63, tr = t >> 6;
    for (int c = tc; c < 152; c += 64){
      float bb = bb11[c], sc = gg11[c] * BNRSQ, tb = tt11[c];
      for (int r = tr; r < 40; r += 4){
        int p = r / 10;
        int j = base + sidx[r];
        float y = Y1[(size_t)j * 152 + c] + Z1[(size_t)(n0 + p) * 152 + c];
        h1[r][c] = gelu_f((y + bb) * sc + tb);
      }
    }
  }
  __syncthreads();
  const int p = t >> 6, kh = (t >> 5) & 1, cg = t & 31;
  const int rbase = p * 10 + kh * 5;
  float acc[5][6];
  #pragma unroll
  for (int k = 0; k < 5; k++)
    #pragma unroll
    for (int j = 0; j < 6; j++) acc[k][j] = 0.f;
  for (int kq = 0; kq < 38; kq++){
    const float* wp = Wr12 + ((size_t)kq * 192 + cg) * 4;
    f4 wv[6];
    #pragma unroll
    for (int j = 0; j < 6; j++) wv[j] = *(const f4*)(wp + j * 128);
    f4 hv[5];
    #pragma unroll
    for (int k = 0; k < 5; k++) hv[k] = *(const f4*)&h1[rbase + k][kq * 4];
    #pragma unroll
    for (int k = 0; k < 5; k++)
      #pragma unroll
      for (int j = 0; j < 6; j++)
        acc[k][j] += hv[k][0] * wv[j][0] + hv[k][1] * wv[j][1]
                   + hv[k][2] * wv[j][2] + hv[k][3] * wv[j][3];
  }
  float ssum = 0.f;
  #pragma unroll
  for (int j = 0; j < 6; j++){
    int c = cg + j * 32;
    float m = 0.f;
    if (c < 181){
      float bb = bb12[c], sc = gg12[c] * BNRSQ, tb = tt12[c];
      m = -3.0e38f;
      #pragma unroll
      for (int k = 0; k < 5; k++){
        float v = gelu_f((acc[k][j] + bb) * sc + tb);
        m = fmaxf(m, v);
      }
    }
    float o = __shfl_xor(m, 32);   // exchange k-halves (lanes 0-31 <-> 32-63)
    m = fmaxf(m, o);
    if (kh == 0){
      float mv = (c < 181) ? m : 0.f;
      x1t[(size_t)(n0 + p) * 192 + c] = mv;
      x1b[(size_t)(n0 + p) * 192 + c] = f2b(mv);
      ssum += mv * mv;
    }
  }
  #pragma unroll
  for (int off = 16; off; off >>= 1) ssum += __shfl_xor(ssum, off);
  if (kh == 0 && cg == 0) sq2[n0 + p] = ssum;
}

// ---------------- stage-2 gather (2-batch group): H2[bl*10+k][448] = gelu(bn(Y[nbr]+Z[bl]))
__global__ __launch_bounds__(256) void h2_k(
    const float* __restrict__ YZ, const int* __restrict__ idx,
    const float* __restrict__ bb21, const float* __restrict__ gg21, const float* __restrict__ tt21,
    short* __restrict__ H2){
  __shared__ int sidx[10];
  int bl = blockIdx.x;
  int t = threadIdx.x;
  if (t < 10) sidx[t] = ((bl >> 11) << 11) + idx[(size_t)bl * 10 + t];
  __syncthreads();
  int cA = t;
  int cB = t + 256;
  float zA = YZ[(size_t)bl * 896 + 448 + cA] + bb21[cA];
  float scA = gg21[cA] * BNRSQ, tbA = tt21[cA];
  float zB = 0.f, scB = 0.f, tbB = 0.f;
  bool realB = cB < 430, padB = cB < 448;
  if (realB){
    zB = YZ[(size_t)bl * 896 + 448 + cB] + bb21[cB];
    scB = gg21[cB] * BNRSQ; tbB = tt21[cB];
  }
  #pragma unroll
  for (int k = 0; k < 10; k++){
    int nb = sidx[k];
    size_t rb = ((size_t)bl * 10 + k) * 448;
    float yA = YZ[(size_t)nb * 896 + cA] + zA;
    H2[rb + cA] = f2b(gelu_f(yA * scA + tbA));
    if (padB){
      short v = 0;
      if (realB){
        float yB = YZ[(size_t)nb * 896 + cB] + zB;
        v = f2b(gelu_f(yB * scB + tbB));
      }
      H2[rb + cB] = v;
    }
  }
}

// ---------------- MFMA GEMM: A[M][Kp] bf16 x Bt[N][Kp] bf16.
// MODE 0: bf16 out, gelu/bn; MODE 1: fp32 out, gelu/bn; MODE 2: fp32 out, raw acc.
template<int MODE>
__global__ __launch_bounds__(256) void gemm_k(const short* __restrict__ A,
                                              const short* __restrict__ Bt,
                                              int Kp, int Nld, int Nreal,
                                              const float* __restrict__ bv,
                                              const float* __restrict__ gv,
                                              const float* __restrict__ tv,
                                              void* __restrict__ outp){
  __shared__ short As[128][40];   // +8 pad: <=2-way bank alias (free)
  __shared__ short Bs[128][40];
  const int t = threadIdx.x;
  const int w = t >> 6, l = t & 63;
  const int m0 = blockIdx.y * 128, n0 = blockIdx.x * 128;
  f32x4 acc[2][8];
  #pragma unroll
  for (int i = 0; i < 2; i++)
    #pragma unroll
    for (int j = 0; j < 8; j++) acc[i][j] = (f32x4)0.f;
  const int ar = t >> 2, akc = t & 3;
  const short* Ag0 = A + (size_t)(m0 + ar) * Kp + akc * 8;
  const short* Ag1 = A + (size_t)(m0 + 64 + ar) * Kp + akc * 8;
  const short* Bg0 = Bt + (size_t)(n0 + ar) * Kp + akc * 8;
  const short* Bg1 = Bt + (size_t)(n0 + 64 + ar) * Kp + akc * 8;
  const int mrow = w * 32 + (l & 15);
  const int kg = (l >> 4) * 8;
  const int cl = l & 15;
  for (int k0 = 0; k0 < Kp; k0 += 32){
    int4 va0 = *(const int4*)(Ag0 + k0);
    int4 va1 = *(const int4*)(Ag1 + k0);
    int4 vb0 = *(const int4*)(Bg0 + k0);
    int4 vb1 = *(const int4*)(Bg1 + k0);
    __syncthreads();
    *(int4*)&As[ar][akc * 8]      = va0;
    *(int4*)&As[ar + 64][akc * 8] = va1;
    *(int4*)&Bs[ar][akc * 8]      = vb0;
    *(int4*)&Bs[ar + 64][akc * 8] = vb1;
    __syncthreads();
    bf16x8 a0 = *(const bf16x8*)&As[mrow][kg];
    bf16x8 a1 = *(const bf16x8*)&As[mrow + 16][kg];
    #pragma unroll
    for (int ni = 0; ni < 8; ni++){
      bf16x8 b = *(const bf16x8*)&Bs[cl + ni * 16][kg];
      acc[0][ni] = __builtin_amdgcn_mfma_f32_16x16x32_bf16(a0, b, acc[0][ni], 0, 0, 0);
      acc[1][ni] = __builtin_amdgcn_mfma_f32_16x16x32_bf16(a1, b, acc[1][ni], 0, 0, 0);
    }
  }
  // epilogue: C[row][col], col=lane&15, row=(lane>>4)*4+reg
  const int rbase = (l >> 4) * 4;
  #pragma unroll
  for (int ni = 0; ni < 8; ni++){
    int n = n0 + ni * 16 + cl;
    float bb = 0.f, sc = 0.f, tb = 0.f;
    if (MODE != 2 && n < Nreal){ bb = bv[n]; sc = gv[n] * BNRSQ; tb = tv[n]; }
    #pragma unroll
    for (int mi = 0; mi < 2; mi++){
      #pragma unroll
      for (int r = 0; r < 4; r++){
        int m = m0 + w * 32 + mi * 16 + rbase + r;
        float a = acc[mi][ni][r];
        float v = (MODE == 2) ? a : gelu_f((a + bb) * sc + tb);
        if (MODE == 0) ((short*)outp)[(size_t)m * Nld + n] = f2b(v);
        else           ((float*)outp)[(size_t)m * Nld + n] = v;
      }
    }
  }
}

// ---------------- k-max over 10 consecutive rows of Pb -> x2b (bf16, bit-exact)
__global__ __launch_bounds__(256) void kmax_k(const short* __restrict__ Pb, short* __restrict__ x2b){
  int p = blockIdx.x;
  int t = threadIdx.x;
  #pragma unroll
  for (int j = 0; j < 2; j++){
    int o = t + j * 256;
    float m = -3.0e38f;
    #pragma unroll
    for (int k = 0; k < 10; k++) m = fmaxf(m, b2f(Pb[((size_t)p * 10 + k) * 512 + o]));
    x2b[(size_t)p * 512 + o] = f2b(m);
  }
}

// ---------------- concat [x1|x2] -> F bf16 [16384][704] (zero pad 693..703)
__global__ __launch_bounds__(256) void fcat_k(const float* __restrict__ x1t, const short* __restrict__ x2b,
                                              short* __restrict__ F){
  size_t g = blockIdx.x;
  int t = threadIdx.x;
  for (int c = t; c < 704; c += 256){
    short v = 0;
    if (c < 181) v = f2b(x1t[g * 192 + c]);
    else if (c < 693) v = x2b[g * 512 + (c - 181)];
    F[g * 704 + c] = v;
  }
}

// ---------------- H6 [16384][512] fp32 -> out (8,512,2048) transposed store
__global__ __launch_bounds__(256) void trout_k(const float* __restrict__ H6, float* __restrict__ out){
  __shared__ float tile[64][65];
  int b = blockIdx.z;
  int nc = blockIdx.x * 64, oc = blockIdx.y * 64;
  int t = threadIdx.x;
  int a = t & 63, r = t >> 6;
  #pragma unroll
  for (int s = 0; s < 16; s++){
    int nl = r + s * 4;
    tile[nl][a] = H6[((size_t)b * 2048 + nc + nl) * 512 + oc + a];
  }
  __syncthreads();
  #pragma unroll
  for (int s = 0; s < 16; s++){
    int ol = r + s * 4;
    out[((size_t)(b * 512 + oc + ol)) * 2048 + nc + a] = tile[a][ol];
  }
}

extern "C" void kernel_launch(void* const* d_in, const int* in_sizes, int n_in,
                              void* d_out, int out_size, void* d_ws, size_t ws_size,
                              hipStream_t stream) {
  const float* x   = (const float*)d_in[0];
  const float* w11 = (const float*)d_in[1];
  const float* b11 = (const float*)d_in[2];
  const float* g11 = (const float*)d_in[3];
  const float* t11 = (const float*)d_in[4];
  const float* w12 = (const float*)d_in[5];
  const float* b12 = (const float*)d_in[6];
  const float* g12 = (const float*)d_in[7];
  const float* t12 = (const float*)d_in[8];
  const float* w21 = (const float*)d_in[9];
  const float* b21 = (const float*)d_in[10];
  const float* g21 = (const float*)d_in[11];
  const float* t21 = (const float*)d_in[12];
  const float* w22 = (const float*)d_in[13];
  const float* b22 = (const float*)d_in[14];
  const float* g22 = (const float*)d_in[15];
  const float* t22 = (const float*)d_in[16];
  const float* w31 = (const float*)d_in[17];
  const float* b31 = (const float*)d_in[18];
  const float* g31 = (const float*)d_in[19];
  const float* t31 = (const float*)d_in[20];
  const float* w32 = (const float*)d_in[21];
  const float* b32 = (const float*)d_in[22];
  const float* g32 = (const float*)d_in[23];
  const float* t32 = (const float*)d_in[24];
  float* out = (float*)d_out;
  char* ws = (char*)d_ws;

  size_t off = 0;
  auto alloc = [&](size_t nbytes) -> char* {
    char* p = ws + off;
    off += ((nbytes + 255) & ~(size_t)255);
    return p;
  };
  // persistent (~40 MB)
  float* x1t  = (float*)alloc((size_t)16384 * 192 * 4);
  short* x1b  = (short*)alloc((size_t)16384 * 192 * 2);
  short* x2b  = (short*)alloc((size_t)16384 * 512 * 2);
  float* sq1  = (float*)alloc(65536);
  float* sq2  = (float*)alloc(65536);
  int*   idx1 = (int*)  alloc(655360);
  int*   idx2 = (int*)  alloc(655360);
  float* WaT11 = (float*)alloc(64 * 152 * 4);
  float* WdT11 = (float*)alloc(64 * 152 * 4);
  float* Wr12  = (float*)alloc(38 * 192 * 4 * 4);
  short* W21sb = (short*)alloc((size_t)896 * 192 * 2);
  short* W22b  = (short*)alloc((size_t)512 * 448 * 2);
  short* W31b  = (short*)alloc((size_t)640 * 704 * 2);
  short* W32b  = (short*)alloc((size_t)512 * 640 * 2);
  // arena (93.3 MB), stage-overlapped
  char* arena = ws + off;
  const size_t ARENA = 93323264;
  if (off + ARENA > ws_size) return;  // visible failure rather than corruption
  // stage-1/2 kNN views: candV | candI (4 batches: 2048*160 each)
  float* candV = (float*)(arena);                   //  5,242,880
  int*   candI = (int*)  (arena + 5242880);         //  5,242,880
  float* Y1    = (float*)(arena + 67108864);        //  9,961,472
  float* Z1    = (float*)(arena + 77070336);        //  9,961,472
  float* xt    = (float*)(arena + 87031808);        //  4,194,304
  // stage-2 compute views (after all topm2 done): Pb | H2b | YZ2g
  short* Pb    = (short*)(arena);                   // 41,943,040 (2-batch group)
  short* H2b   = (short*)(arena + 41943040);        // 36,700,160
  float* YZ2g  = (float*)(arena + 78643200);        // 14,680,064
  // stage-3 views: F | H5 | H6
  short* F     = (short*)(arena);                   // 23,068,672
  short* H5    = (short*)(arena + 23068672);        // 20,971,520
  float* H6    = (float*)(arena + 44040192);        // 33,554,432

  prep_k<<<dim3(2750), dim3(256), 0, stream>>>(w11, w12, w21, w22, w31, w32,
                                               WaT11, WdT11, Wr12, W21sb, W22b, W31b, W32b);

  transpose_k<<<dim3(32, 8), dim3(256), 0, stream>>>(x, xt);
  sqnorm_k<<<dim3(4096), dim3(256), 0, stream>>>(xt, sq1, 64, 64, 16384);

  // stage-1 kNN: 2 launches of 4 batches (dist+blocktop10 -> merge)
  for (int pb = 0; pb < 2; pb++){
    dist_k<<<dim3(16, 16, 4), dim3(256), 0, stream>>>(xt + (size_t)pb * 4 * 2048 * 64,
                                                      sq1 + pb * 8192, candV, candI, 64, 64);
    topm_k<<<dim3(512, 4), dim3(256), 0, stream>>>(candV, candI, idx1 + (size_t)pb * 4 * 20480);
  }
  yz_k<<<dim3(3, 256), dim3(256), 0, stream>>>(xt, 64, WaT11, WdT11, 152, Y1, Z1);
  fused1_k<<<dim3(4096), dim3(256), 0, stream>>>(Y1, Z1, idx1, Wr12,
                                                 b11, g11, t11, b12, g12, t12,
                                                 x1t, x1b, sq2);

  // stage-2 kNN: 2 launches of 4 batches
  for (int pb = 0; pb < 2; pb++){
    dist_k<<<dim3(16, 16, 4), dim3(256), 0, stream>>>(x1t + (size_t)pb * 4 * 2048 * 192,
                                                      sq2 + pb * 8192, candV, candI, 192, 192);
    topm_k<<<dim3(512, 4), dim3(256), 0, stream>>>(candV, candI, idx2 + (size_t)pb * 4 * 20480);
  }
  // stage-2 compute: 4 groups of 2 batches
  for (int g = 0; g < 4; g++){
    gemm_k<2><<<dim3(7, 32), dim3(256), 0, stream>>>(x1b + (size_t)g * 4096 * 192, W21sb,
                                                     192, 896, 896,
                                                     nullptr, nullptr, nullptr, (void*)YZ2g);
    h2_k<<<dim3(4096), dim3(256), 0, stream>>>(YZ2g, idx2 + (size_t)g * 40960,
                                               b21, g21, t21, H2b);
    gemm_k<0><<<dim3(4, 320), dim3(256), 0, stream>>>(H2b, W22b, 448, 512, 512,
                                                      b22, g22, t22, (void*)Pb);
    kmax_k<<<dim3(4096), dim3(256), 0, stream>>>(Pb, x2b + (size_t)g * 4096 * 512);
  }

  fcat_k<<<dim3(16384), dim3(256), 0, stream>>>(x1t, x2b, F);
  gemm_k<0><<<dim3(5, 128), dim3(256), 0, stream>>>(F, W31b, 704, 640, 595,
                                                    b31, g31, t31, (void*)H5);
  gemm_k<1><<<dim3(4, 128), dim3(256), 0, stream>>>(H5, W32b, 640, 512, 512,
                                                    b32, g32, t32, (void*)H6);
  trout_k<<<dim3(32, 8, 8), dim3(256), 0, stream>>>(H6, out);
}

// Round 19
// 1079.717 us; speedup vs baseline: 1.4052x; 1.4052x over previous
//
#include <hip/hip_runtime.h>

// GCNEncoder — round 19: exact restore of round-17 (best known: 1081us).
// r18's fused block-top10 REGRESSED (1517us): per-thread 8-row x 10-iter shfl
// butterfly = ~3000 VALU + 320 DS-pipe shfl per thread; dist 221us/launch,
// VALU 51%, occ 26%. HBM round-trip (16.8MB/batch) is ~8x cheaper. Reverted.
// State: fused1 219us (compiler codegen plateau, parked); kNN fp32-bound
// (bit-stability required for neighbor selection); GEMMs bf16-MFMA.

typedef float f4 __attribute__((ext_vector_type(4)));
typedef float f32x4 __attribute__((ext_vector_type(4)));
typedef short bf16x8 __attribute__((ext_vector_type(8)));

#define BNRSQ 0.9999950000374997f  // 1/sqrt(1+1e-5)

__device__ __forceinline__ float gelu_f(float x){
  float a = 0.7978845608028654f * (x + 0.044715f * x * x * x);
  float e = __expf(2.0f * a);
  float t = 1.0f - 2.0f / (e + 1.0f);   // tanh(a), safe at +/-inf
  return 0.5f * x * (1.0f + t);
}

__device__ __forceinline__ short f2b(float x){            // fp32 -> bf16 RNE
  unsigned u = __float_as_uint(x);
  unsigned r = (u + 0x7fffu + ((u >> 16) & 1u)) >> 16;
  return (short)r;
}
__device__ __forceinline__ float b2f(short s){
  return __uint_as_float(((unsigned)(unsigned short)s) << 16);
}

// ---------------- merged weight prep (segmented by blockIdx.x; 2750 blocks total)
__global__ void prep_k(const float* __restrict__ w11, const float* __restrict__ w12,
                       const float* __restrict__ w21, const float* __restrict__ w22,
                       const float* __restrict__ w31, const float* __restrict__ w32,
                       float* __restrict__ WaT11, float* __restrict__ WdT11,
                       float* __restrict__ Wr12, short* __restrict__ W21sb,
                       short* __restrict__ W22b, short* __restrict__ W31b,
                       short* __restrict__ W32b){
  const int bid = blockIdx.x;
  const int t = threadIdx.x;
  if (bid < 76){
    int split = bid >= 38;
    int id = (split ? bid - 38 : bid) * 256 + t;
    if (id < 64 * 152){
      int c = id / 152, o = id - c * 152;
      float w0 = w11[(size_t)o * 128 + c];
      float v = split ? (w11[(size_t)o * 128 + 64 + c] - w0) : w0;
      (split ? WdT11 : WaT11)[id] = v;
    }
  } else if (bid < 190){
    int id = (bid - 76) * 256 + t;
    if (id < 38 * 192 * 4){
      int i = id & 3, c = (id >> 2) % 192, kq = id / 768;
      int k = kq * 4 + i;
      float v = 0.f;
      if (c < 181 && k < 152) v = w12[(size_t)c * 152 + k];
      Wr12[id] = v;
    }
  } else if (bid < 1086){
    int n = bid - 190;
    if (t < 192){
      short v = 0;
      if (t < 181){
        if (n < 430) v = f2b(w21[(size_t)n * 362 + t]);
        else if (n >= 448 && n < 878){
          int m = n - 448;
          v = f2b(w21[(size_t)m * 362 + 181 + t] - w21[(size_t)m * 362 + t]);
        }
      }
      W21sb[(size_t)n * 192 + t] = v;
    }
  } else if (bid < 1598){
    int n = bid - 1086;
    for (int k = t; k < 448; k += 256){
      short v = 0;
      if (k < 430) v = f2b(w22[(size_t)n * 430 + k]);
      W22b[(size_t)n * 448 + k] = v;
    }
  } else if (bid < 2238){
    int n = bid - 1598;
    for (int k = t; k < 704; k += 256){
      short v = 0;
      if (n < 595 && k < 693) v = f2b(w31[(size_t)n * 693 + k]);
      W31b[(size_t)n * 704 + k] = v;
    }
  } else {
    int n = bid - 2238;
    for (int k = t; k < 640; k += 256){
      short v = 0;
      if (k < 595) v = f2b(w32[(size_t)n * 595 + k]);
      W32b[(size_t)n * 640 + k] = v;
    }
  }
}

// ---------------- transpose (B,64,2048) -> (B,2048,64)
__global__ __launch_bounds__(256) void transpose_k(const float* __restrict__ x, float* __restrict__ xt){
  __shared__ float tile[64][65];
  int b = blockIdx.y;
  int n0 = blockIdx.x * 64;
  int t = threadIdx.x;
  int a = t & 63, r = t >> 6;
  #pragma unroll
  for (int s = 0; s < 16; s++){
    int c = r + s * 4;
    tile[c][a] = x[((size_t)b * 64 + c) * 2048 + n0 + a];
  }
  __syncthreads();
  #pragma unroll
  for (int s = 0; s < 16; s++){
    int n = r + s * 4;
    xt[((size_t)b * 2048 + n0 + n) * 64 + a] = tile[a][n];
  }
}

// ---------------- row squared norms (wave per row), ld-aware
__global__ __launch_bounds__(256) void sqnorm_k(const float* __restrict__ X, float* __restrict__ sq,
                                                int C, int ld, int npts){
  int gid = blockIdx.x * blockDim.x + threadIdx.x;
  int wid = gid >> 6, lane = gid & 63;
  if (wid >= npts) return;
  const float* row = X + (size_t)wid * ld;
  float s = 0.f;
  for (int c = lane; c < C; c += 64){ float v = row[c]; s += v * v; }
  #pragma unroll
  for (int off = 32; off; off >>= 1) s += __shfl_xor(s, off);
  if (lane == 0) sq[wid] = s;
}

// ---------------- dist: 128x128 tile, 8x8 acc, batches via z. C % 16 == 0.
__global__ __launch_bounds__(256) void dist_k(const float* __restrict__ X, const float* __restrict__ sq,
                                              float* __restrict__ dist, int C, int ldx){
  __shared__ float As[16][132];
  __shared__ float Bs[16][132];
  const int z = blockIdx.z;
  const float* Xb = X + (size_t)z * 2048 * ldx;
  const float* sqb = sq + (z << 11);
  float* db = dist + (size_t)z * 2048 * 2048;
  const int i0 = blockIdx.y * 128, j0 = blockIdx.x * 128;
  const int t = threadIdx.x;
  const int ti = t >> 4, tj = t & 15;
  const int r = t & 127, q8 = (t >> 7) * 8;
  float acc[2][2][4][4];
  #pragma unroll
  for (int a = 0; a < 2; a++)
    #pragma unroll
    for (int b = 0; b < 2; b++)
      #pragma unroll
      for (int u = 0; u < 4; u++)
        #pragma unroll
        for (int v = 0; v < 4; v++) acc[a][b][u][v] = 0.f;
  const float* Ag = Xb + (size_t)(i0 + r) * ldx + q8;
  const float* Bg = Xb + (size_t)(j0 + r) * ldx + q8;
  for (int c0 = 0; c0 < C; c0 += 16){
    f4 av0 = *(const f4*)(Ag + c0);
    f4 av1 = *(const f4*)(Ag + c0 + 4);
    f4 bv0 = *(const f4*)(Bg + c0);
    f4 bv1 = *(const f4*)(Bg + c0 + 4);
    __syncthreads();
    #pragma unroll
    for (int i = 0; i < 4; i++){
      As[q8 + i][r] = av0[i];  As[q8 + 4 + i][r] = av1[i];
      Bs[q8 + i][r] = bv0[i];  Bs[q8 + 4 + i][r] = bv1[i];
    }
    __syncthreads();
    #pragma unroll
    for (int k = 0; k < 16; k++){
      f4 a0 = *(const f4*)&As[k][ti * 4];
      f4 a1 = *(const f4*)&As[k][ti * 4 + 64];
      f4 b0 = *(const f4*)&Bs[k][tj * 4];
      f4 b1 = *(const f4*)&Bs[k][tj * 4 + 64];
      #pragma unroll
      for (int u = 0; u < 4; u++)
        #pragma unroll
        for (int v = 0; v < 4; v++){
          acc[0][0][u][v] += a0[u] * b0[v];
          acc[0][1][u][v] += a0[u] * b1[v];
          acc[1][0][u][v] += a1[u] * b0[v];
          acc[1][1][u][v] += a1[u] * b1[v];
        }
    }
  }
  #pragma unroll
  for (int ia = 0; ia < 2; ia++){
    #pragma unroll
    for (int u = 0; u < 4; u++){
      int i = i0 + ia * 64 + ti * 4 + u;
      float si = sqb[i];
      #pragma unroll
      for (int jb = 0; jb < 2; jb++){
        int j = j0 + jb * 64 + tj * 4;
        f4 o;
        #pragma unroll
        for (int v = 0; v < 4; v++) o[v] = si + sqb[j + v] - 2.0f * acc[ia][jb][u][v];
        *(f4*)&db[(size_t)i * 2048 + j] = o;
      }
    }
  }
}

// ---------------- top-10 smallest per row (wave per row), batches via y
__global__ __launch_bounds__(256) void topk_k(const float* __restrict__ dist, int* __restrict__ idxout){
  int z = blockIdx.y;
  int lane = threadIdx.x & 63;
  int row = blockIdx.x * 4 + (threadIdx.x >> 6);
  const float* d = dist + (size_t)z * 2048 * 2048 + (size_t)row * 2048;
  float v[32];
  #pragma unroll
  for (int s = 0; s < 32; s++) v[s] = d[s * 64 + lane];
  int* outp = idxout + (size_t)z * 20480 + (size_t)row * 10;
  for (int it = 0; it < 10; ++it){
    float bv = 3.0e38f; int bi = 0x7fffffff;
    #pragma unroll
    for (int s = 0; s < 32; s++){
      if (v[s] < bv){ bv = v[s]; bi = s * 64 + lane; }
    }
    #pragma unroll
    for (int off = 32; off; off >>= 1){
      float ov = __shfl_xor(bv, off);
      int   oi = __shfl_xor(bi, off);
      if (ov < bv || (ov == bv && oi < bi)){ bv = ov; bi = oi; }
    }
    #pragma unroll
    for (int s = 0; s < 32; s++) if (s * 64 + lane == bi) v[s] = 3.0e38f;
    if (lane == 0) outp[it] = bi;
  }
}

// ---------------- dual GEMM fp32 (stage-1 only): Y = A*B1, Z = A*B2
__global__ __launch_bounds__(256) void yz_k(const float* __restrict__ Amat, int C,
                                            const float* __restrict__ B1, const float* __restrict__ B2,
                                            int O, float* __restrict__ Y, float* __restrict__ Z){
  __shared__ float As[16][68];
  __shared__ float B1s[16][68];
  __shared__ float B2s[16][68];
  int m0 = blockIdx.y * 64, o0 = blockIdx.x * 64;
  int t = threadIdx.x;
  int cc = t & 15, rr = t >> 4;
  int oo = t & 63, kk = t >> 6;
  float accY[4][4], accZ[4][4];
  #pragma unroll
  for (int u = 0; u < 4; u++)
    #pragma unroll
    for (int v = 0; v < 4; v++){ accY[u][v] = 0.f; accZ[u][v] = 0.f; }
  for (int c0 = 0; c0 < C; c0 += 16){
    #pragma unroll
    for (int u = 0; u < 4; u++){
      int ii = rr + u * 16;
      As[cc][ii] = ((c0 + cc) < C) ? Amat[(size_t)(m0 + ii) * C + c0 + cc] : 0.f;
    }
    #pragma unroll
    for (int u = 0; u < 4; u++){
      int c = kk * 4 + u;
      bool ok = ((c0 + c) < C) && ((o0 + oo) < O);
      B1s[c][oo] = ok ? B1[(size_t)(c0 + c) * O + o0 + oo] : 0.f;
      B2s[c][oo] = ok ? B2[(size_t)(c0 + c) * O + o0 + oo] : 0.f;
    }
    __syncthreads();
    #pragma unroll
    for (int k = 0; k < 16; k++){
      f4 a  = *(const f4*)&As[k][rr * 4];
      f4 b1 = *(const f4*)&B1s[k][cc * 4];
      f4 b2 = *(const f4*)&B2s[k][cc * 4];
      #pragma unroll
      for (int u = 0; u < 4; u++)
        #pragma unroll
        for (int v = 0; v < 4; v++){
          accY[u][v] += a[u] * b1[v];
          accZ[u][v] += a[u] * b2[v];
        }
    }
    __syncthreads();
  }
  #pragma unroll
  for (int u = 0; u < 4; u++){
    int m = m0 + rr * 4 + u;
    #pragma unroll
    for (int v = 0; v < 4; v++){
      int o = o0 + cc * 4 + v;
      if (o < O){
        Y[(size_t)m * O + o] = accY[u][v];
        Z[(size_t)m * O + o] = accZ[u][v];
      }
    }
  }
}

// ---------------- stage-1 fused v5 (fp32, r14-exact): 4 pts/block, kh half-wave k-split,
// cg 32 colgroups, acc[5][6]. LDS 24.5KB -> 6 blocks/CU. Epilogue: x1t + x1b + sq2.
__global__ __launch_bounds__(256) void fused1_k(
    const float* __restrict__ Y1, const float* __restrict__ Z1,
    const int* __restrict__ idx, const float* __restrict__ Wr12,
    const float* __restrict__ bb11, const float* __restrict__ gg11, const float* __restrict__ tt11,
    const float* __restrict__ bb12, const float* __restrict__ gg12, const float* __restrict__ tt12,
    float* __restrict__ x1t, short* __restrict__ x1b, float* __restrict__ sq2){
  __shared__ float h1[40][152];
  __shared__ int sidx[40];
  const int n0 = blockIdx.x * 4;
  const int t = threadIdx.x;
  if (t < 40) sidx[t] = idx[(size_t)n0 * 10 + t];
  __syncthreads();
  const int base = (n0 >> 11) << 11;
  {
    const int tc = t & 63, tr = t >> 6;
    for (int c = tc; c < 152; c += 64){
      float bb = bb11[c], sc = gg11[c] * BNRSQ, tb = tt11[c];
      for (int r = tr; r < 40; r += 4){
        int p = r / 10;
        int j = base + sidx[r];
        float y = Y1[(size_t)j * 152 + c] + Z1[(size_t)(n0 + p) * 152 + c];
        h1[r][c] = gelu_f((y + bb) * sc + tb);
      }
    }
  }
  __syncthreads();
  const int p = t >> 6, kh = (t >> 5) & 1, cg = t & 31;
  const int rbase = p * 10 + kh * 5;
  float acc[5][6];
  #pragma unroll
  for (int k = 0; k < 5; k++)
    #pragma unroll
    for (int j = 0; j < 6; j++) acc[k][j] = 0.f;
  for (int kq = 0; kq < 38; kq++){
    const float* wp = Wr12 + ((size_t)kq * 192 + cg) * 4;
    f4 wv[6];
    #pragma unroll
    for (int j = 0; j < 6; j++) wv[j] = *(const f4*)(wp + j * 128);
    f4 hv[5];
    #pragma unroll
    for (int k = 0; k < 5; k++) hv[k] = *(const f4*)&h1[rbase + k][kq * 4];
    #pragma unroll
    for (int k = 0; k < 5; k++)
      #pragma unroll
      for (int j = 0; j < 6; j++)
        acc[k][j] += hv[k][0] * wv[j][0] + hv[k][1] * wv[j][1]
                   + hv[k][2] * wv[j][2] + hv[k][3] * wv[j][3];
  }
  float ssum = 0.f;
  #pragma unroll
  for (int j = 0; j < 6; j++){
    int c = cg + j * 32;
    float m = 0.f;
    if (c < 181){
      float bb = bb12[c], sc = gg12[c] * BNRSQ, tb = tt12[c];
      m = -3.0e38f;
      #pragma unroll
      for (int k = 0; k < 5; k++){
        float v = gelu_f((acc[k][j] + bb) * sc + tb);
        m = fmaxf(m, v);
      }
    }
    float o = __shfl_xor(m, 32);   // exchange k-halves (lanes 0-31 <-> 32-63)
    m = fmaxf(m, o);
    if (kh == 0){
      float mv = (c < 181) ? m : 0.f;
      x1t[(size_t)(n0 + p) * 192 + c] = mv;
      x1b[(size_t)(n0 + p) * 192 + c] = f2b(mv);
      ssum += mv * mv;
    }
  }
  #pragma unroll
  for (int off = 16; off; off >>= 1) ssum += __shfl_xor(ssum, off);
  if (kh == 0 && cg == 0) sq2[n0 + p] = ssum;
}

// ---------------- stage-2 gather (2-batch group): H2[bl*10+k][448] = gelu(bn(Y[nbr]+Z[bl]))
__global__ __launch_bounds__(256) void h2_k(
    const float* __restrict__ YZ, const int* __restrict__ idx,
    const float* __restrict__ bb21, const float* __restrict__ gg21, const float* __restrict__ tt21,
    short* __restrict__ H2){
  __shared__ int sidx[10];
  int bl = blockIdx.x;
  int t = threadIdx.x;
  if (t < 10) sidx[t] = ((bl >> 11) << 11) + idx[(size_t)bl * 10 + t];
  __syncthreads();
  int cA = t;
  int cB = t + 256;
  float zA = YZ[(size_t)bl * 896 + 448 + cA] + bb21[cA];
  float scA = gg21[cA] * BNRSQ, tbA = tt21[cA];
  float zB = 0.f, scB = 0.f, tbB = 0.f;
  bool realB = cB < 430, padB = cB < 448;
  if (realB){
    zB = YZ[(size_t)bl * 896 + 448 + cB] + bb21[cB];
    scB = gg21[cB] * BNRSQ; tbB = tt21[cB];
  }
  #pragma unroll
  for (int k = 0; k < 10; k++){
    int nb = sidx[k];
    size_t rb = ((size_t)bl * 10 + k) * 448;
    float yA = YZ[(size_t)nb * 896 + cA] + zA;
    H2[rb + cA] = f2b(gelu_f(yA * scA + tbA));
    if (padB){
      short v = 0;
      if (realB){
        float yB = YZ[(size_t)nb * 896 + cB] + zB;
        v = f2b(gelu_f(yB * scB + tbB));
      }
      H2[rb + cB] = v;
    }
  }
}

// ---------------- MFMA GEMM: A[M][Kp] bf16 x Bt[N][Kp] bf16.
// MODE 0: bf16 out, gelu/bn; MODE 1: fp32 out, gelu/bn; MODE 2: fp32 out, raw acc.
template<int MODE>
__global__ __launch_bounds__(256) void gemm_k(const short* __restrict__ A,
                                              const short* __restrict__ Bt,
                                              int Kp, int Nld, int Nreal,
                                              const float* __restrict__ bv,
                                              const float* __restrict__ gv,
                                              const float* __restrict__ tv,
                                              void* __restrict__ outp){
  __shared__ short As[128][40];   // +8 pad: <=2-way bank alias (free)
  __shared__ short Bs[128][40];
  const int t = threadIdx.x;
  const int w = t >> 6, l = t & 63;
  const int m0 = blockIdx.y * 128, n0 = blockIdx.x * 128;
  f32x4 acc[2][8];
  #pragma unroll
  for (int i = 0; i < 2; i++)
    #pragma unroll
    for (int j = 0; j < 8; j++) acc[i][j] = (f32x4)0.f;
  const int ar = t >> 2, akc = t & 3;
  const short* Ag0 = A + (size_t)(m0 + ar) * Kp + akc * 8;
  const short* Ag1 = A + (size_t)(m0 + 64 + ar) * Kp + akc * 8;
  const short* Bg0 = Bt + (size_t)(n0 + ar) * Kp + akc * 8;
  const short* Bg1 = Bt + (size_t)(n0 + 64 + ar) * Kp + akc * 8;
  const int mrow = w * 32 + (l & 15);
  const int kg = (l >> 4) * 8;
  const int cl = l & 15;
  for (int k0 = 0; k0 < Kp; k0 += 32){
    int4 va0 = *(const int4*)(Ag0 + k0);
    int4 va1 = *(const int4*)(Ag1 + k0);
    int4 vb0 = *(const int4*)(Bg0 + k0);
    int4 vb1 = *(const int4*)(Bg1 + k0);
    __syncthreads();
    *(int4*)&As[ar][akc * 8]      = va0;
    *(int4*)&As[ar + 64][akc * 8] = va1;
    *(int4*)&Bs[ar][akc * 8]      = vb0;
    *(int4*)&Bs[ar + 64][akc * 8] = vb1;
    __syncthreads();
    bf16x8 a0 = *(const bf16x8*)&As[mrow][kg];
    bf16x8 a1 = *(const bf16x8*)&As[mrow + 16][kg];
    #pragma unroll
    for (int ni = 0; ni < 8; ni++){
      bf16x8 b = *(const bf16x8*)&Bs[cl + ni * 16][kg];
      acc[0][ni] = __builtin_amdgcn_mfma_f32_16x16x32_bf16(a0, b, acc[0][ni], 0, 0, 0);
      acc[1][ni] = __builtin_amdgcn_mfma_f32_16x16x32_bf16(a1, b, acc[1][ni], 0, 0, 0);
    }
  }
  // epilogue: C[row][col], col=lane&15, row=(lane>>4)*4+reg
  const int rbase = (l >> 4) * 4;
  #pragma unroll
  for (int ni = 0; ni < 8; ni++){
    int n = n0 + ni * 16 + cl;
    float bb = 0.f, sc = 0.f, tb = 0.f;
    if (MODE != 2 && n < Nreal){ bb = bv[n]; sc = gv[n] * BNRSQ; tb = tv[n]; }
    #pragma unroll
    for (int mi = 0; mi < 2; mi++){
      #pragma unroll
      for (int r = 0; r < 4; r++){
        int m = m0 + w * 32 + mi * 16 + rbase + r;
        float a = acc[mi][ni][r];
        float v = (MODE == 2) ? a : gelu_f((a + bb) * sc + tb);
        if (MODE == 0) ((short*)outp)[(size_t)m * Nld + n] = f2b(v);
        else           ((float*)outp)[(size_t)m * Nld + n] = v;
      }
    }
  }
}

// ---------------- k-max over 10 consecutive rows of Pb -> x2b (bf16, bit-exact)
__global__ __launch_bounds__(256) void kmax_k(const short* __restrict__ Pb, short* __restrict__ x2b){
  int p = blockIdx.x;
  int t = threadIdx.x;
  #pragma unroll
  for (int j = 0; j < 2; j++){
    int o = t + j * 256;
    float m = -3.0e38f;
    #pragma unroll
    for (int k = 0; k < 10; k++) m = fmaxf(m, b2f(Pb[((size_t)p * 10 + k) * 512 + o]));
    x2b[(size_t)p * 512 + o] = f2b(m);
  }
}

// ---------------- concat [x1|x2] -> F bf16 [16384][704] (zero pad 693..703)
__global__ __launch_bounds__(256) void fcat_k(const float* __restrict__ x1t, const short* __restrict__ x2b,
                                              short* __restrict__ F){
  size_t g = blockIdx.x;
  int t = threadIdx.x;
  for (int c = t; c < 704; c += 256){
    short v = 0;
    if (c < 181) v = f2b(x1t[g * 192 + c]);
    else if (c < 693) v = x2b[g * 512 + (c - 181)];
    F[g * 704 + c] = v;
  }
}

// ---------------- H6 [16384][512] fp32 -> out (8,512,2048) transposed store
__global__ __launch_bounds__(256) void trout_k(const float* __restrict__ H6, float* __restrict__ out){
  __shared__ float tile[64][65];
  int b = blockIdx.z;
  int nc = blockIdx.x * 64, oc = blockIdx.y * 64;
  int t = threadIdx.x;
  int a = t & 63, r = t >> 6;
  #pragma unroll
  for (int s = 0; s < 16; s++){
    int nl = r + s * 4;
    tile[nl][a] = H6[((size_t)b * 2048 + nc + nl) * 512 + oc + a];
  }
  __syncthreads();
  #pragma unroll
  for (int s = 0; s < 16; s++){
    int ol = r + s * 4;
    out[((size_t)(b * 512 + oc + ol)) * 2048 + nc + a] = tile[a][ol];
  }
}

extern "C" void kernel_launch(void* const* d_in, const int* in_sizes, int n_in,
                              void* d_out, int out_size, void* d_ws, size_t ws_size,
                              hipStream_t stream) {
  const float* x   = (const float*)d_in[0];
  const float* w11 = (const float*)d_in[1];
  const float* b11 = (const float*)d_in[2];
  const float* g11 = (const float*)d_in[3];
  const float* t11 = (const float*)d_in[4];
  const float* w12 = (const float*)d_in[5];
  const float* b12 = (const float*)d_in[6];
  const float* g12 = (const float*)d_in[7];
  const float* t12 = (const float*)d_in[8];
  const float* w21 = (const float*)d_in[9];
  const float* b21 = (const float*)d_in[10];
  const float* g21 = (const float*)d_in[11];
  const float* t21 = (const float*)d_in[12];
  const float* w22 = (const float*)d_in[13];
  const float* b22 = (const float*)d_in[14];
  const float* g22 = (const float*)d_in[15];
  const float* t22 = (const float*)d_in[16];
  const float* w31 = (const float*)d_in[17];
  const float* b31 = (const float*)d_in[18];
  const float* g31 = (const float*)d_in[19];
  const float* t31 = (const float*)d_in[20];
  const float* w32 = (const float*)d_in[21];
  const float* b32 = (const float*)d_in[22];
  const float* g32 = (const float*)d_in[23];
  const float* t32 = (const float*)d_in[24];
  float* out = (float*)d_out;
  char* ws = (char*)d_ws;

  size_t off = 0;
  auto alloc = [&](size_t nbytes) -> char* {
    char* p = ws + off;
    off += ((nbytes + 255) & ~(size_t)255);
    return p;
  };
  // persistent (~40 MB)
  float* x1t  = (float*)alloc((size_t)16384 * 192 * 4);
  short* x1b  = (short*)alloc((size_t)16384 * 192 * 2);
  short* x2b  = (short*)alloc((size_t)16384 * 512 * 2);
  float* sq1  = (float*)alloc(65536);
  float* sq2  = (float*)alloc(65536);
  int*   idx1 = (int*)  alloc(655360);
  int*   idx2 = (int*)  alloc(655360);
  float* WaT11 = (float*)alloc(64 * 152 * 4);
  float* WdT11 = (float*)alloc(64 * 152 * 4);
  float* Wr12  = (float*)alloc(38 * 192 * 4 * 4);
  short* W21sb = (short*)alloc((size_t)896 * 192 * 2);
  short* W22b  = (short*)alloc((size_t)512 * 448 * 2);
  short* W31b  = (short*)alloc((size_t)640 * 704 * 2);
  short* W32b  = (short*)alloc((size_t)512 * 640 * 2);
  // arena (93.3 MB), stage-overlapped
  char* arena = ws + off;
  const size_t ARENA = 93323264;
  if (off + ARENA > ws_size) return;  // visible failure rather than corruption
  // stage-1 views: distP | Y1 | Z1 | xt
  float* distP = (float*)(arena);                   // 4 batches: 67,108,864
  float* Y1    = (float*)(arena + 67108864);        //  9,961,472
  float* Z1    = (float*)(arena + 77070336);        //  9,961,472
  float* xt    = (float*)(arena + 87031808);        //  4,194,304
  // stage-2 views (after all topk2 done): Pb | H2b | YZ2g
  short* Pb    = (short*)(arena);                   // 41,943,040 (2-batch group)
  short* H2b   = (short*)(arena + 41943040);        // 36,700,160
  float* YZ2g  = (float*)(arena + 78643200);        // 14,680,064
  // stage-3 views: F | H5 | H6
  short* F     = (short*)(arena);                   // 23,068,672
  short* H5    = (short*)(arena + 23068672);        // 20,971,520
  float* H6    = (float*)(arena + 44040192);        // 33,554,432

  prep_k<<<dim3(2750), dim3(256), 0, stream>>>(w11, w12, w21, w22, w31, w32,
                                               WaT11, WdT11, Wr12, W21sb, W22b, W31b, W32b);

  transpose_k<<<dim3(32, 8), dim3(256), 0, stream>>>(x, xt);
  sqnorm_k<<<dim3(4096), dim3(256), 0, stream>>>(xt, sq1, 64, 64, 16384);

  // stage-1 kNN: 2 launches of 4 batches
  for (int pb = 0; pb < 2; pb++){
    dist_k<<<dim3(16, 16, 4), dim3(256), 0, stream>>>(xt + (size_t)pb * 4 * 2048 * 64,
                                                      sq1 + pb * 8192, distP, 64, 64);
    topk_k<<<dim3(512, 4), dim3(256), 0, stream>>>(distP, idx1 + (size_t)pb * 4 * 20480);
  }
  yz_k<<<dim3(3, 256), dim3(256), 0, stream>>>(xt, 64, WaT11, WdT11, 152, Y1, Z1);
  fused1_k<<<dim3(4096), dim3(256), 0, stream>>>(Y1, Z1, idx1, Wr12,
                                                 b11, g11, t11, b12, g12, t12,
                                                 x1t, x1b, sq2);

  // stage-2 kNN: 2 launches of 4 batches
  for (int pb = 0; pb < 2; pb++){
    dist_k<<<dim3(16, 16, 4), dim3(256), 0, stream>>>(x1t + (size_t)pb * 4 * 2048 * 192,
                                                      sq2 + pb * 8192, distP, 192, 192);
    topk_k<<<dim3(512, 4), dim3(256), 0, stream>>>(distP, idx2 + (size_t)pb * 4 * 20480);
  }
  // stage-2 compute: 4 groups of 2 batches
  for (int g = 0; g < 4; g++){
    gemm_k<2><<<dim3(7, 32), dim3(256), 0, stream>>>(x1b + (size_t)g * 4096 * 192, W21sb,
                                                     192, 896, 896,
                                                     nullptr, nullptr, nullptr, (void*)YZ2g);
    h2_k<<<dim3(4096), dim3(256), 0, stream>>>(YZ2g, idx2 + (size_t)g * 40960,
                                               b21, g21, t21, H2b);
    gemm_k<0><<<dim3(4, 320), dim3(256), 0, stream>>>(H2b, W22b, 448, 512, 512,
                                                      b22, g22, t22, (void*)Pb);
    kmax_k<<<dim3(4096), dim3(256), 0, stream>>>(Pb, x2b + (size_t)g * 4096 * 512);
  }

  fcat_k<<<dim3(16384), dim3(256), 0, stream>>>(x1t, x2b, F);
  gemm_k<0><<<dim3(5, 128), dim3(256), 0, stream>>>(F, W31b, 704, 640, 595,
                                                    b31, g31, t31, (void*)H5);
  gemm_k<1><<<dim3(4, 128), dim3(256), 0, stream>>>(H5, W32b, 640, 512, 512,
                                                    b32, g32, t32, (void*)H6);
  trout_k<<<dim3(32, 8, 8), dim3(256), 0, stream>>>(H6, out);
}